// Round 1
// baseline (275.047 us; speedup 1.0000x reference)
//
#include <hip/hip_runtime.h>
#include <hip/hip_bf16.h>

// ---- types ----
typedef __bf16 bf16x8 __attribute__((ext_vector_type(8)));
typedef __bf16 bf16x4 __attribute__((ext_vector_type(4)));
typedef float  f32x4  __attribute__((ext_vector_type(4)));

#define MFMA16(a, b, c) __builtin_amdgcn_mfma_f32_16x16x32_bf16((a), (b), (c), 0, 0, 0)

// Problem constants
#define BATCH 16
#define SEQ   1024
#define VD    1024
#define TD    768
#define HDIM  512
#define MROWS (BATCH * SEQ)   // 16384

typedef __attribute__((address_space(1))) const unsigned int gas_uint;
typedef __attribute__((address_space(3))) unsigned int las_uint;

__device__ __forceinline__ void async_copy16(const void* g, void* l) {
    // global -> LDS direct copy, 16B per lane; LDS dest = wave-uniform base + lane*16
    __builtin_amdgcn_global_load_lds((gas_uint*)g, (las_uint*)l, 16, 0, 0);
}

// ---------------------------------------------------------------------------
// Projection GEMM (NT): C[M][512] = X[M][K] * W[512][K]^T + bias, out bf16.
// 128x128 tile per 256-thread block, 4 waves in 2x2, each wave 64x64 (4x4 MFMA).
// Staging converts fp32 -> bf16 on the fly (manual ds_write).
// ---------------------------------------------------------------------------
template <int K>
__global__ __launch_bounds__(256) void proj_kernel(const float* __restrict__ X,
                                                   const float* __restrict__ W,
                                                   const float* __restrict__ bias,
                                                   __bf16* __restrict__ out) {
    __shared__ __bf16 As[128 * 32];
    __shared__ __bf16 Bs[128 * 32];

    const int n0   = blockIdx.x * 128;
    const int m0   = blockIdx.y * 128;
    const int tid  = threadIdx.x;
    const int lane = tid & 63;
    const int wave = tid >> 6;
    const int wr   = wave >> 1;   // wave row (0..1)
    const int wc   = wave & 1;    // wave col (0..1)
    const int fr   = lane & 15;   // fragment row/col
    const int fq   = lane >> 4;   // quad -> k part

    f32x4 acc[4][4] = {};

    for (int kk = 0; kk < K; kk += 32) {
        // stage A and B tiles: 128x32 fp32 each -> bf16 LDS
#pragma unroll
        for (int it = 0; it < 4; ++it) {
            const int f   = tid + it * 256;   // 0..1023 (float4 index)
            const int row = f >> 3;           // 8 float4 per 32-col row
            const int c4  = f & 7;
            const float4 xa = *reinterpret_cast<const float4*>(&X[(size_t)(m0 + row) * K + kk + c4 * 4]);
            bf16x4 pa = {(__bf16)xa.x, (__bf16)xa.y, (__bf16)xa.z, (__bf16)xa.w};
            *reinterpret_cast<bf16x4*>(&As[row * 32 + c4 * 4]) = pa;
            const float4 xb = *reinterpret_cast<const float4*>(&W[(size_t)(n0 + row) * K + kk + c4 * 4]);
            bf16x4 pb = {(__bf16)xb.x, (__bf16)xb.y, (__bf16)xb.z, (__bf16)xb.w};
            *reinterpret_cast<bf16x4*>(&Bs[row * 32 + c4 * 4]) = pb;
        }
        __syncthreads();

        bf16x8 a[4], b[4];
#pragma unroll
        for (int t = 0; t < 4; ++t) {
            a[t] = *reinterpret_cast<const bf16x8*>(&As[(wr * 64 + t * 16 + fr) * 32 + fq * 8]);
            b[t] = *reinterpret_cast<const bf16x8*>(&Bs[(wc * 64 + t * 16 + fr) * 32 + fq * 8]);
        }
#pragma unroll
        for (int tm = 0; tm < 4; ++tm)
#pragma unroll
            for (int tn = 0; tn < 4; ++tn)
                acc[tm][tn] = MFMA16(a[tm], b[tn], acc[tm][tn]);
        __syncthreads();
    }

    // epilogue: add bias, store bf16. D layout: col = lane&15, row = (lane>>4)*4 + reg
#pragma unroll
    for (int tn = 0; tn < 4; ++tn) {
        const int col  = n0 + wc * 64 + tn * 16 + fr;
        const float bc = bias[col];
#pragma unroll
        for (int tm = 0; tm < 4; ++tm) {
            const int rowb = m0 + wr * 64 + tm * 16 + fq * 4;
#pragma unroll
            for (int r = 0; r < 4; ++r) {
                out[(size_t)(rowb + r) * HDIM + col] = (__bf16)(acc[tm][tn][r] + bc);
            }
        }
    }
}

// ---------------------------------------------------------------------------
// Row L2 norms of v and t (bf16 [16384][512]) -> fp32. One wave per row.
// ---------------------------------------------------------------------------
__global__ __launch_bounds__(256) void norm_kernel(const __bf16* __restrict__ v,
                                                   const __bf16* __restrict__ t,
                                                   float* __restrict__ vn,
                                                   float* __restrict__ tn) {
    const int g    = blockIdx.x * 4 + (threadIdx.x >> 6);  // global wave id, 0..32767
    const int lane = threadIdx.x & 63;
    const __bf16* src = v;
    float* dst = vn;
    int row = g;
    if (g >= MROWS) { src = t; dst = tn; row = g - MROWS; }
    const bf16x8 x = *reinterpret_cast<const bf16x8*>(&src[(size_t)row * HDIM + lane * 8]);
    float s = 0.f;
#pragma unroll
    for (int j = 0; j < 8; ++j) {
        const float f = (float)x[j];
        s = fmaf(f, f, s);
    }
#pragma unroll
    for (int off = 32; off > 0; off >>= 1) s += __shfl_down(s, off);
    if (lane == 0) dst[row] = sqrtf(s);
}

// ---------------------------------------------------------------------------
// Batched dots GEMM (NT): out[b][i][j] = sum_h v[b,i,h]*t[b,j,h] / max(vn_i*tn_j, eps)
// 128x128 tile, K=512, bf16 inputs staged via global_load_lds (16B/lane).
// ---------------------------------------------------------------------------
__global__ __launch_bounds__(256) void dots_kernel(const __bf16* __restrict__ v,
                                                   const __bf16* __restrict__ t,
                                                   const float* __restrict__ vn,
                                                   const float* __restrict__ tn,
                                                   float* __restrict__ out) {
    __shared__ __bf16 As[128 * 32];
    __shared__ __bf16 Bs[128 * 32];

    const int b  = blockIdx.z;
    const int j0 = blockIdx.x * 128;
    const int i0 = blockIdx.y * 128;
    const __bf16* vb = v + (size_t)b * SEQ * HDIM;
    const __bf16* tb = t + (size_t)b * SEQ * HDIM;

    const int tid  = threadIdx.x;
    const int lane = tid & 63;
    const int wave = tid >> 6;
    const int wr   = wave >> 1;
    const int wc   = wave & 1;
    const int fr   = lane & 15;
    const int fq   = lane >> 4;

    f32x4 acc[4][4] = {};

    for (int kk = 0; kk < HDIM; kk += 32) {
        // async stage: each tile is 512 chunks of 16B; wave w handles chunks [w*128, w*128+128)
#pragma unroll
        for (int s = 0; s < 2; ++s) {
            const int c    = (wave * 2 + s) * 64 + lane;  // chunk id 0..511
            const int row  = c >> 2;                      // 4 chunks per 32-elem row
            const int part = c & 3;
            async_copy16(&vb[(size_t)(i0 + row) * HDIM + kk + part * 8],
                         &As[(wave * 2 + s) * 512]);
            async_copy16(&tb[(size_t)(j0 + row) * HDIM + kk + part * 8],
                         &Bs[(wave * 2 + s) * 512]);
        }
        __syncthreads();

        bf16x8 a[4], bfr[4];
#pragma unroll
        for (int t_ = 0; t_ < 4; ++t_) {
            a[t_]   = *reinterpret_cast<const bf16x8*>(&As[(wr * 64 + t_ * 16 + fr) * 32 + fq * 8]);
            bfr[t_] = *reinterpret_cast<const bf16x8*>(&Bs[(wc * 64 + t_ * 16 + fr) * 32 + fq * 8]);
        }
#pragma unroll
        for (int tm = 0; tm < 4; ++tm)
#pragma unroll
            for (int tn_ = 0; tn_ < 4; ++tn_)
                acc[tm][tn_] = MFMA16(a[tm], bfr[tn_], acc[tm][tn_]);
        __syncthreads();
    }

    // epilogue: divide by max(vn_i * tn_j, eps), store fp32
    float vr[16];
#pragma unroll
    for (int tm = 0; tm < 4; ++tm)
#pragma unroll
        for (int r = 0; r < 4; ++r)
            vr[tm * 4 + r] = vn[b * SEQ + i0 + wr * 64 + tm * 16 + fq * 4 + r];

    float* outb = out + ((size_t)b << 20);
#pragma unroll
    for (int tn_ = 0; tn_ < 4; ++tn_) {
        const int j    = j0 + wc * 64 + tn_ * 16 + fr;
        const float tj = tn[b * SEQ + j];
#pragma unroll
        for (int tm = 0; tm < 4; ++tm) {
            const int ib = i0 + wr * 64 + tm * 16 + fq * 4;
#pragma unroll
            for (int r = 0; r < 4; ++r) {
                const float denom = fmaxf(vr[tm * 4 + r] * tj, 1e-8f);
                outb[(size_t)(ib + r) * SEQ + j] = acc[tm][tn_][r] * __builtin_amdgcn_rcpf(denom);
            }
        }
    }
}

// ---------------------------------------------------------------------------
extern "C" void kernel_launch(void* const* d_in, const int* in_sizes, int n_in,
                              void* d_out, int out_size, void* d_ws, size_t ws_size,
                              hipStream_t stream) {
    const float* Xv = (const float*)d_in[0];  // [16,1024,1024]
    const float* Xt = (const float*)d_in[1];  // [16,1024,768]
    const float* Wv = (const float*)d_in[2];  // [512,1024]
    const float* bv = (const float*)d_in[3];  // [512]
    const float* Wt = (const float*)d_in[4];  // [512,768]
    const float* bt = (const float*)d_in[5];  // [512]
    float* out = (float*)d_out;               // [16,1024,1024]

    char* ws = (char*)d_ws;
    __bf16* v  = (__bf16*)ws;                                   // 16 MiB
    __bf16* t  = (__bf16*)(ws + (size_t)MROWS * HDIM * 2);      // 16 MiB
    float*  vn = (float*)(ws + (size_t)2 * MROWS * HDIM * 2);   // 64 KiB
    float*  tn = (float*)(ws + (size_t)2 * MROWS * HDIM * 2 + (size_t)MROWS * 4);

    // 1) projections (grid: x = n-tiles (512/128=4), y = m-tiles (16384/128=128))
    proj_kernel<VD><<<dim3(4, 128), 256, 0, stream>>>(Xv, Wv, bv, v);
    proj_kernel<TD><<<dim3(4, 128), 256, 0, stream>>>(Xt, Wt, bt, t);

    // 2) row norms (32768 waves)
    norm_kernel<<<8192, 256, 0, stream>>>(v, t, vn, tn);

    // 3) batched dots + normalize (grid: 8x8 tiles x 16 batches)
    dots_kernel<<<dim3(8, 8, BATCH), 256, 0, stream>>>(v, t, vn, tn, out);
}

// Round 2
// 267.286 us; speedup vs baseline: 1.0290x; 1.0290x over previous
//
#include <hip/hip_runtime.h>
#include <hip/hip_bf16.h>

// ---- types ----
typedef __bf16 bf16x8 __attribute__((ext_vector_type(8)));
typedef __bf16 bf16x4 __attribute__((ext_vector_type(4)));
typedef float  f32x4  __attribute__((ext_vector_type(4)));

#define MFMA16(a, b, c) __builtin_amdgcn_mfma_f32_16x16x32_bf16((a), (b), (c), 0, 0, 0)

// Problem constants
#define BATCH 16
#define SEQ   1024
#define VD    1024
#define TD    768
#define HDIM  512
#define MROWS (BATCH * SEQ)   // 16384

typedef __attribute__((address_space(1))) const unsigned int gas_uint;
typedef __attribute__((address_space(3))) unsigned int las_uint;

__device__ __forceinline__ void async_copy16(const void* g, void* l) {
    __builtin_amdgcn_global_load_lds((gas_uint*)g, (las_uint*)l, 16, 0, 0);
}

// ---------------------------------------------------------------------------
// Fused dual projection GEMM (NT): C[M][512] = X[M][K] * W[512][K]^T + bias,
// out bf16. blockIdx.z picks (Xv,Wv,bv)->v or (Xt,Wt,bt)->t.
// 128x128 tile / 256 threads / 4 waves 2x2, each wave 64x64 (4x4 MFMA).
// K-loop: register prefetch of tile k+1 overlapping MFMA(k), double-buffered
// LDS, ONE barrier per iteration.
// ---------------------------------------------------------------------------
__global__ __launch_bounds__(256) void proj_dual_kernel(
    const float* __restrict__ Xv, const float* __restrict__ Wv, const float* __restrict__ bv_,
    const float* __restrict__ Xt, const float* __restrict__ Wt, const float* __restrict__ bt_,
    __bf16* __restrict__ vout, __bf16* __restrict__ tout)
{
    const float *X, *W, *bias;
    __bf16* out;
    int K;
    if (blockIdx.z == 0) { X = Xv; W = Wv; bias = bv_; out = vout; K = VD; }
    else                 { X = Xt; W = Wt; bias = bt_; out = tout; K = TD; }

    __shared__ __bf16 As[2][128 * 32];
    __shared__ __bf16 Bs[2][128 * 32];

    const int n0   = blockIdx.x * 128;
    const int m0   = blockIdx.y * 128;
    const int tid  = threadIdx.x;
    const int lane = tid & 63;
    const int wave = tid >> 6;
    const int wr   = wave >> 1;
    const int wc   = wave & 1;
    const int fr   = lane & 15;
    const int fq   = lane >> 4;

    // per-thread staging coordinates (4 chunks of float4 per array)
    int srow[4], sc4[4];
#pragma unroll
    for (int it = 0; it < 4; ++it) {
        const int f = tid + it * 256;   // 0..1023
        srow[it] = f >> 3;              // 8 float4 per 32-col row
        sc4[it]  = f & 7;
    }

    float4 ra[4], rb[4];

    // ---- preload + stage tile 0 into buffer 0 ----
#pragma unroll
    for (int it = 0; it < 4; ++it) {
        ra[it] = *reinterpret_cast<const float4*>(&X[(size_t)(m0 + srow[it]) * K + sc4[it] * 4]);
        rb[it] = *reinterpret_cast<const float4*>(&W[(size_t)(n0 + srow[it]) * K + sc4[it] * 4]);
    }
#pragma unroll
    for (int it = 0; it < 4; ++it) {
        bf16x4 pa = {(__bf16)ra[it].x, (__bf16)ra[it].y, (__bf16)ra[it].z, (__bf16)ra[it].w};
        *reinterpret_cast<bf16x4*>(&As[0][srow[it] * 32 + sc4[it] * 4]) = pa;
        bf16x4 pb = {(__bf16)rb[it].x, (__bf16)rb[it].y, (__bf16)rb[it].z, (__bf16)rb[it].w};
        *reinterpret_cast<bf16x4*>(&Bs[0][srow[it] * 32 + sc4[it] * 4]) = pb;
    }
    __syncthreads();

    f32x4 acc[4][4] = {};
    const int nk = K >> 5;

    for (int ki = 0; ki < nk - 1; ++ki) {
        const int kk = (ki + 1) << 5;
        // prefetch tile k+1 into registers (latency overlaps MFMA below)
#pragma unroll
        for (int it = 0; it < 4; ++it) {
            ra[it] = *reinterpret_cast<const float4*>(&X[(size_t)(m0 + srow[it]) * K + kk + sc4[it] * 4]);
            rb[it] = *reinterpret_cast<const float4*>(&W[(size_t)(n0 + srow[it]) * K + kk + sc4[it] * 4]);
        }

        // MFMA on current buffer
        const __bf16* Ab = As[ki & 1];
        const __bf16* Bb = Bs[ki & 1];
        bf16x8 a[4], b[4];
#pragma unroll
        for (int t_ = 0; t_ < 4; ++t_) {
            a[t_] = *reinterpret_cast<const bf16x8*>(&Ab[(wr * 64 + t_ * 16 + fr) * 32 + fq * 8]);
            b[t_] = *reinterpret_cast<const bf16x8*>(&Bb[(wc * 64 + t_ * 16 + fr) * 32 + fq * 8]);
        }
#pragma unroll
        for (int tm = 0; tm < 4; ++tm)
#pragma unroll
            for (int tn = 0; tn < 4; ++tn)
                acc[tm][tn] = MFMA16(a[tm], b[tn], acc[tm][tn]);

        // stage prefetched tile into the other buffer
        __bf16* Aw = As[(ki + 1) & 1];
        __bf16* Bw = Bs[(ki + 1) & 1];
#pragma unroll
        for (int it = 0; it < 4; ++it) {
            bf16x4 pa = {(__bf16)ra[it].x, (__bf16)ra[it].y, (__bf16)ra[it].z, (__bf16)ra[it].w};
            *reinterpret_cast<bf16x4*>(&Aw[srow[it] * 32 + sc4[it] * 4]) = pa;
            bf16x4 pb = {(__bf16)rb[it].x, (__bf16)rb[it].y, (__bf16)rb[it].z, (__bf16)rb[it].w};
            *reinterpret_cast<bf16x4*>(&Bw[srow[it] * 32 + sc4[it] * 4]) = pb;
        }
        __syncthreads();
    }

    // final tile
    {
        const __bf16* Ab = As[(nk - 1) & 1];
        const __bf16* Bb = Bs[(nk - 1) & 1];
        bf16x8 a[4], b[4];
#pragma unroll
        for (int t_ = 0; t_ < 4; ++t_) {
            a[t_] = *reinterpret_cast<const bf16x8*>(&Ab[(wr * 64 + t_ * 16 + fr) * 32 + fq * 8]);
            b[t_] = *reinterpret_cast<const bf16x8*>(&Bb[(wc * 64 + t_ * 16 + fr) * 32 + fq * 8]);
        }
#pragma unroll
        for (int tm = 0; tm < 4; ++tm)
#pragma unroll
            for (int tn = 0; tn < 4; ++tn)
                acc[tm][tn] = MFMA16(a[tm], b[tn], acc[tm][tn]);
    }

    // epilogue: add bias, store bf16. D layout: col = lane&15, row = (lane>>4)*4 + reg
#pragma unroll
    for (int tn = 0; tn < 4; ++tn) {
        const int col  = n0 + wc * 64 + tn * 16 + fr;
        const float bc = bias[col];
#pragma unroll
        for (int tm = 0; tm < 4; ++tm) {
            const int rowb = m0 + wr * 64 + tm * 16 + fq * 4;
#pragma unroll
            for (int r = 0; r < 4; ++r) {
                out[(size_t)(rowb + r) * HDIM + col] = (__bf16)(acc[tm][tn][r] + bc);
            }
        }
    }
}

// ---------------------------------------------------------------------------
// Row L2 norms of v and t (bf16 [16384][512]) -> fp32. One wave per row.
// ---------------------------------------------------------------------------
__global__ __launch_bounds__(256) void norm_kernel(const __bf16* __restrict__ v,
                                                   const __bf16* __restrict__ t,
                                                   float* __restrict__ vn,
                                                   float* __restrict__ tn) {
    const int g    = blockIdx.x * 4 + (threadIdx.x >> 6);
    const int lane = threadIdx.x & 63;
    const __bf16* src = v;
    float* dst = vn;
    int row = g;
    if (g >= MROWS) { src = t; dst = tn; row = g - MROWS; }
    const bf16x8 x = *reinterpret_cast<const bf16x8*>(&src[(size_t)row * HDIM + lane * 8]);
    float s = 0.f;
#pragma unroll
    for (int j = 0; j < 8; ++j) {
        const float f = (float)x[j];
        s = fmaf(f, f, s);
    }
#pragma unroll
    for (int off = 32; off > 0; off >>= 1) s += __shfl_down(s, off);
    if (lane == 0) dst[row] = sqrtf(s);
}

// ---------------------------------------------------------------------------
// Batched dots GEMM (NT): out[b][i][j] = sum_h v[b,i,h]*t[b,j,h] / max(vn_i*tn_j, eps)
// 128x128 tile, K=512, bf16 inputs staged via global_load_lds (16B/lane).
// ---------------------------------------------------------------------------
__global__ __launch_bounds__(256) void dots_kernel(const __bf16* __restrict__ v,
                                                   const __bf16* __restrict__ t,
                                                   const float* __restrict__ vn,
                                                   const float* __restrict__ tn,
                                                   float* __restrict__ out) {
    __shared__ __bf16 As[128 * 32];
    __shared__ __bf16 Bs[128 * 32];

    const int b  = blockIdx.z;
    const int j0 = blockIdx.x * 128;
    const int i0 = blockIdx.y * 128;
    const __bf16* vb = v + (size_t)b * SEQ * HDIM;
    const __bf16* tb = t + (size_t)b * SEQ * HDIM;

    const int tid  = threadIdx.x;
    const int lane = tid & 63;
    const int wave = tid >> 6;
    const int wr   = wave >> 1;
    const int wc   = wave & 1;
    const int fr   = lane & 15;
    const int fq   = lane >> 4;

    f32x4 acc[4][4] = {};

    for (int kk = 0; kk < HDIM; kk += 32) {
#pragma unroll
        for (int s = 0; s < 2; ++s) {
            const int c    = (wave * 2 + s) * 64 + lane;
            const int row  = c >> 2;
            const int part = c & 3;
            async_copy16(&vb[(size_t)(i0 + row) * HDIM + kk + part * 8],
                         &As[(wave * 2 + s) * 512]);
            async_copy16(&tb[(size_t)(j0 + row) * HDIM + kk + part * 8],
                         &Bs[(wave * 2 + s) * 512]);
        }
        __syncthreads();

        bf16x8 a[4], bfr[4];
#pragma unroll
        for (int t_ = 0; t_ < 4; ++t_) {
            a[t_]   = *reinterpret_cast<const bf16x8*>(&As[(wr * 64 + t_ * 16 + fr) * 32 + fq * 8]);
            bfr[t_] = *reinterpret_cast<const bf16x8*>(&Bs[(wc * 64 + t_ * 16 + fr) * 32 + fq * 8]);
        }
#pragma unroll
        for (int tm = 0; tm < 4; ++tm)
#pragma unroll
            for (int tn_ = 0; tn_ < 4; ++tn_)
                acc[tm][tn_] = MFMA16(a[tm], bfr[tn_], acc[tm][tn_]);
        __syncthreads();
    }

    float vr[16];
#pragma unroll
    for (int tm = 0; tm < 4; ++tm)
#pragma unroll
        for (int r = 0; r < 4; ++r)
            vr[tm * 4 + r] = vn[b * SEQ + i0 + wr * 64 + tm * 16 + fq * 4 + r];

    float* outb = out + ((size_t)b << 20);
#pragma unroll
    for (int tn_ = 0; tn_ < 4; ++tn_) {
        const int j    = j0 + wc * 64 + tn_ * 16 + fr;
        const float tj = tn[b * SEQ + j];
#pragma unroll
        for (int tm = 0; tm < 4; ++tm) {
            const int ib = i0 + wr * 64 + tm * 16 + fq * 4;
#pragma unroll
            for (int r = 0; r < 4; ++r) {
                const float denom = fmaxf(vr[tm * 4 + r] * tj, 1e-8f);
                outb[(size_t)(ib + r) * SEQ + j] = acc[tm][tn_][r] * __builtin_amdgcn_rcpf(denom);
            }
        }
    }
}

// ---------------------------------------------------------------------------
extern "C" void kernel_launch(void* const* d_in, const int* in_sizes, int n_in,
                              void* d_out, int out_size, void* d_ws, size_t ws_size,
                              hipStream_t stream) {
    const float* Xv = (const float*)d_in[0];  // [16,1024,1024]
    const float* Xt = (const float*)d_in[1];  // [16,1024,768]
    const float* Wv = (const float*)d_in[2];  // [512,1024]
    const float* bv = (const float*)d_in[3];  // [512]
    const float* Wt = (const float*)d_in[4];  // [512,768]
    const float* bt = (const float*)d_in[5];  // [512]
    float* out = (float*)d_out;               // [16,1024,1024]

    char* ws = (char*)d_ws;
    __bf16* v  = (__bf16*)ws;                                   // 16 MiB
    __bf16* t  = (__bf16*)(ws + (size_t)MROWS * HDIM * 2);      // 16 MiB
    float*  vn = (float*)(ws + (size_t)2 * MROWS * HDIM * 2);   // 64 KiB
    float*  tn = (float*)(ws + (size_t)2 * MROWS * HDIM * 2 + (size_t)MROWS * 4);

    // 1) fused projections: grid (n-tiles=4, m-tiles=128, z=2) = 1024 blocks
    proj_dual_kernel<<<dim3(4, 128, 2), 256, 0, stream>>>(Xv, Wv, bv, Xt, Wt, bt, v, t);

    // 2) row norms (32768 waves)
    norm_kernel<<<8192, 256, 0, stream>>>(v, t, vn, tn);

    // 3) batched dots + normalize (grid: 8x8 tiles x 16 batches)
    dots_kernel<<<dim3(8, 8, BATCH), 256, 0, stream>>>(v, t, vn, tn, out);
}